// Round 2
// baseline (25.173 us; speedup 1.0000x reference)
//
#include <hip/hip_runtime.h>
#include <hip/hip_bf16.h>
#include <math.h>

// Shapes fixed by reference: B=2, L=385, C=128, N=384, 2C=256
// Identity used (verified in round 0, passed):
//   out[b,1+i,c] = Kc[b,c] + sum_k F[b,i,k] * WbT[b][k][c]
//   WbT[k][c] = gamma[C+k]*W[c,C+k] - s_k*W[c,k],   s_k = gamma[k]/sqrt(var_j F[:,k] + eps)
//   Kc[c]     = b[c] + sum_k ( W[c,k]*u[k] + W[c,C+k]*beta[C+k] ),  u = s*M + beta[k]
//   M[k]      = sum_j softmax_j(s_k F[j,k]) * F[j,k]
// Single fused kernel: each block redundantly computes per-batch stats with
// coalesced reads, then does its 16-row tile of the K=128 GEMM.

#define B_  2
#define L_  385
#define C_  128
#define N_  384
#define EPS_ 1e-5f
#define ROWS_ 16
#define RB_  (N_ / ROWS_)          // 24 row-tiles per batch
#define NTHR_ 1024
#define JPT_ (N_ / 8)              // 48 rows per h-group per pass

__global__ __launch_bounds__(NTHR_, 1) void lnp_fused_kernel(
    const float* __restrict__ x, const float* __restrict__ gamma,
    const float* __restrict__ beta, const float* __restrict__ W,
    const float* __restrict__ bvec, float* __restrict__ out) {
  __shared__ float p_s1[8][128];
  __shared__ float p_s2[8][128];
  __shared__ float p_mn[8][128];
  __shared__ float p_mx[8][128];
  __shared__ float sA[128], mxL[128], uA[128], KcS[128];
  __shared__ float kcp[128][2];
  __shared__ float WbT[128][129];   // [k][c], pad -> conflict-free both ways
  __shared__ float Fs[ROWS_][128];

  const int blk = blockIdx.x;
  const int b   = blk / RB_;
  const int rt  = blk % RB_;
  const int r0  = rt * ROWS_;
  const int t   = threadIdx.x;
  const int c0  = t & 127;   // channel this thread owns in stats phases
  const int h   = t >> 7;    // row-group 0..7

  const float* Fb = x + (size_t)b * L_ * C_ + C_;   // F[b][j][c] = Fb[j*128+c]

  // ---- Stage F tile for GEMM (coalesced; consumed after later barriers) ----
#pragma unroll
  for (int idx = t; idx < ROWS_ * 128; idx += NTHR_) {
    Fs[idx >> 7][idx & 127] = Fb[(size_t)(r0 + (idx >> 7)) * 128 + (idx & 127)];
  }

  // ---- cls-token passthrough ----
  if (rt == 0 && t < 128) {
    out[(size_t)b * L_ * C_ + t] = x[(size_t)b * L_ * C_ + t];
  }

  // ---- Pass 1: sum / sumsq / min / max per channel (coalesced rows) ----
  {
    float s1 = 0.f, s2 = 0.f, mn = INFINITY, mx = -INFINITY;
#pragma unroll 4
    for (int jj = 0; jj < JPT_; ++jj) {
      const float f = Fb[(size_t)(h * JPT_ + jj) * 128 + c0];
      s1 += f;
      s2 = fmaf(f, f, s2);
      mn = fminf(mn, f);
      mx = fmaxf(mx, f);
    }
    p_s1[h][c0] = s1; p_s2[h][c0] = s2; p_mn[h][c0] = mn; p_mx[h][c0] = mx;
  }
  __syncthreads();
  if (t < 128) {
    float s1 = 0.f, s2 = 0.f, mn = INFINITY, mx = -INFINITY;
#pragma unroll
    for (int g = 0; g < 8; ++g) {
      s1 += p_s1[g][t]; s2 += p_s2[g][t];
      mn = fminf(mn, p_mn[g][t]); mx = fmaxf(mx, p_mx[g][t]);
    }
    const float mean = s1 * (1.0f / N_);
    float var = s2 * (1.0f / N_) - mean * mean;
    var = fmaxf(var, 0.0f);
    const float s = gamma[t] * rsqrtf(var + EPS_);
    sA[t]  = s;
    mxL[t] = (s >= 0.f) ? s * mx : s * mn;
  }
  __syncthreads();

  // ---- Pass 2: softmax moments per channel ----
  {
    const float s = sA[c0];
    const float ml = mxL[c0];
    float se = 0.f, sef = 0.f;
#pragma unroll 4
    for (int jj = 0; jj < JPT_; ++jj) {
      const float f = Fb[(size_t)(h * JPT_ + jj) * 128 + c0];
      const float e = expf(fmaf(s, f, -ml));
      se += e;
      sef = fmaf(e, f, sef);
    }
    p_s1[h][c0] = se; p_s2[h][c0] = sef;
  }
  __syncthreads();
  if (t < 128) {
    float se = 0.f, sef = 0.f;
#pragma unroll
    for (int g = 0; g < 8; ++g) { se += p_s1[g][t]; sef += p_s2[g][t]; }
    const float M = sef / se;
    uA[t] = fmaf(sA[t], M, beta[t]);
  }
  __syncthreads();

  // ---- WbT build + folded Kc reduction ----
  {
    const int k    = t & 127;
    const int g    = t >> 7;
    const int lane = t & 63;
    const int wpar = (t >> 6) & 1;
    const float ga = gamma[128 + k];
    const float be = beta[128 + k];
    const float aK = sA[k];
    const float uK = uA[k];
#pragma unroll 4
    for (int it = 0; it < 16; ++it) {
      const int cW = g + 8 * it;
      const float* wr = W + cW * 256 + k;
      const float W1 = wr[0];
      const float W2 = wr[128];
      WbT[k][cW] = fmaf(ga, W2, -aK * W1);
      float kt = fmaf(W1, uK, W2 * be);
#pragma unroll
      for (int off = 32; off; off >>= 1) kt += __shfl_xor(kt, off);
      if (lane == 0) kcp[cW][wpar] = kt;
    }
  }
  __syncthreads();
  if (t < 128) KcS[t] = bvec[t] + kcp[t][0] + kcp[t][1];
  __syncthreads();

  // ---- GEMM: 2 rows per thread, K=128 ----
  {
    const int cc = t & 127;
    const int rg = t >> 7;
    const int ra = rg * 2, rb2 = rg * 2 + 1;
    float acc0 = 0.f, acc1 = 0.f;
#pragma unroll 8
    for (int k = 0; k < 128; ++k) {
      const float wv = WbT[k][cc];          // vector read, conflict-free
      acc0 = fmaf(wv, Fs[ra][k], acc0);     // wave broadcast
      acc1 = fmaf(wv, Fs[rb2][k], acc1);    // wave broadcast
    }
    const float kc = KcS[cc];
    float* o0 = out + (size_t)b * L_ * C_ + (size_t)(1 + r0 + ra) * 128;
    float* o1 = out + (size_t)b * L_ * C_ + (size_t)(1 + r0 + rb2) * 128;
    o0[cc] = acc0 + kc;
    o1[cc] = acc1 + kc;
  }
}

extern "C" void kernel_launch(void* const* d_in, const int* in_sizes, int n_in,
                              void* d_out, int out_size, void* d_ws, size_t ws_size,
                              hipStream_t stream) {
  const float* x     = (const float*)d_in[0];
  const float* gamma = (const float*)d_in[1];
  const float* beta  = (const float*)d_in[2];
  const float* W     = (const float*)d_in[3];
  const float* bvec  = (const float*)d_in[4];
  float* out = (float*)d_out;

  lnp_fused_kernel<<<B_ * RB_, NTHR_, 0, stream>>>(x, gamma, beta, W, bvec, out);
}

// Round 3
// 23.893 us; speedup vs baseline: 1.0536x; 1.0536x over previous
//
#include <hip/hip_runtime.h>
#include <hip/hip_bf16.h>
#include <math.h>

// Shapes fixed by reference: B=2, L=385, C=128, N=384, 2C=256
// Verified identity (round 0/1/2 all passed with it):
//   out[b,1+i,c] = Kc[b,c] + sum_{kk=0}^{255} A2[b,i,kk] * W[c,kk]
//     A2[i,kk]  = -s_kk * F[i,kk]          (kk < 128)
//     A2[i,kk]  =  gamma[kk] * F[i,kk-128] (kk >= 128)
//     s_k       = gamma[k] / sqrt(var_j F[:,k] + eps)
//     Kc[c]     = b[c] + sum_k ( W[c,k]*u[k] + W[c,128+k]*beta[128+k] )
//     u[k]      = s_k*M_k + beta[k],  M_k = sum_j softmax_j(s_k F[j,k]) F[j,k]
// Single kernel, 24 blocks x 1024 thr. GEMM via bf16 MFMA 16x16x32 with
// XOR-swizzled LDS operands (A2, Wbf). Stats computed redundantly per block
// with coalesced reads (cheap: all of x is L2-resident).

#define B_  2
#define L_  385
#define C_  128
#define N_  384
#define EPS_ 1e-5f
#define MROWS_ 32
#define RB_  (N_ / MROWS_)   // 12 row-tiles per batch
#define NTHR_ 1024
#define JPT_ (N_ / 8)        // 48 rows per h-group in stats passes

typedef short short8 __attribute__((ext_vector_type(8)));
typedef float f32x4 __attribute__((ext_vector_type(4)));

union V16 { ushort us[8]; uint4 v4; };

__device__ inline ushort f2bf(float f) {  // f32 -> bf16, round-nearest-even
  uint32_t u = __builtin_bit_cast(uint32_t, f);
  u += 0x7fffu + ((u >> 16) & 1u);
  return (ushort)(u >> 16);
}

__global__ __launch_bounds__(NTHR_, 1) void lnp_mfma_kernel(
    const float* __restrict__ x, const float* __restrict__ gamma,
    const float* __restrict__ beta, const float* __restrict__ W,
    const float* __restrict__ bvec, float* __restrict__ out) {
  __shared__ float p_s1[8][128], p_s2[8][128], p_mn[8][128], p_mx[8][128];
  __shared__ float sA[128], mxL[128], uA[128], KcS[128];
  __shared__ float kcp[128][8];
  __shared__ __align__(16) ushort Wb[128 * 256];    // [c][kk^((c&7)<<3)] bf16
  __shared__ __align__(16) ushort As[MROWS_ * 256]; // [i][kk^((i&7)<<3)] bf16

  const int blk = blockIdx.x;
  const int b   = blk / RB_;
  const int rt  = blk % RB_;
  const int r0  = rt * MROWS_;
  const int t   = threadIdx.x;
  const int c0  = t & 127;
  const int h   = t >> 7;

  const float* Fb = x + (size_t)b * (L_ * C_) + C_;  // F[j][c] = Fb[j*128+c]

  // cls-token passthrough
  if (rt == 0 && t < C_)
    out[(size_t)b * (L_ * C_) + t] = x[(size_t)b * (L_ * C_) + t];

  // ---- Pass 1: per-channel sum / sumsq / min / max (coalesced) ----
  {
    float s1 = 0.f, s2 = 0.f, mn = INFINITY, mx = -INFINITY;
#pragma unroll 4
    for (int jj = 0; jj < JPT_; ++jj) {
      const float f = Fb[(size_t)(h * JPT_ + jj) * C_ + c0];
      s1 += f; s2 = fmaf(f, f, s2);
      mn = fminf(mn, f); mx = fmaxf(mx, f);
    }
    p_s1[h][c0] = s1; p_s2[h][c0] = s2; p_mn[h][c0] = mn; p_mx[h][c0] = mx;
  }
  __syncthreads();
  if (t < 128) {
    float s1 = 0.f, s2 = 0.f, mn = INFINITY, mx = -INFINITY;
#pragma unroll
    for (int g = 0; g < 8; ++g) {
      s1 += p_s1[g][t]; s2 += p_s2[g][t];
      mn = fminf(mn, p_mn[g][t]); mx = fmaxf(mx, p_mx[g][t]);
    }
    const float mean = s1 * (1.0f / N_);
    float var = fmaxf(s2 * (1.0f / N_) - mean * mean, 0.0f);
    const float s = gamma[t] * rsqrtf(var + EPS_);
    sA[t]  = s;
    mxL[t] = (s >= 0.f) ? s * mx : s * mn;
  }
  __syncthreads();

  // ---- Pass 2: softmax moments ----
  {
    const float s = sA[c0], ml = mxL[c0];
    float se = 0.f, sef = 0.f;
#pragma unroll 4
    for (int jj = 0; jj < JPT_; ++jj) {
      const float f = Fb[(size_t)(h * JPT_ + jj) * C_ + c0];
      const float e = expf(fmaf(s, f, -ml));
      se += e; sef = fmaf(e, f, sef);
    }
    p_s1[h][c0] = se; p_s2[h][c0] = sef;
  }
  __syncthreads();
  if (t < 128) {
    float se = 0.f, sef = 0.f;
#pragma unroll
    for (int g = 0; g < 8; ++g) { se += p_s1[g][t]; sef += p_s2[g][t]; }
    uA[t] = fmaf(sA[t], sef / se, beta[t]);
  }
  __syncthreads();

  // ---- Build Wbf (bf16, swizzled) + Kc partials; build A2 (bf16, swizzled) --
  {
    // W conversion: thread owns row c = t>>3, 32-kk segment seg = t&7
    const int c   = t >> 3;
    const int seg = t & 7;
    const int kb  = seg * 32;
    float part = 0.f;
#pragma unroll
    for (int q = 0; q < 4; ++q) {
      const int kk = kb + q * 8;
      const float* wp = &W[c * 256 + kk];
      const float4 wa = *(const float4*)wp;
      const float4 wb2 = *(const float4*)(wp + 4);
      const float v[8] = {wa.x, wa.y, wa.z, wa.w, wb2.x, wb2.y, wb2.z, wb2.w};
      V16 pk;
#pragma unroll
      for (int j = 0; j < 8; ++j) {
        const int kkj = kk + j;
        pk.us[j] = f2bf(v[j]);
        part = fmaf(v[j], (kkj < 128 ? uA[kkj] : beta[kkj]), part);
      }
      *(uint4*)&Wb[c * 256 + (kk ^ ((c & 7) << 3))] = pk.v4;
    }
    kcp[c][seg] = part;
  }
  {
    // A2: thread owns row i = t>>5, 8-kk chunk kk0 = (t&31)*8
    const int i   = t >> 5;
    const int kk0 = (t & 31) * 8;
    const int ks  = (kk0 < 128) ? kk0 : kk0 - 128;
    const float* fp = &Fb[(size_t)(r0 + i) * C_ + ks];
    const float4 fa = *(const float4*)fp;
    const float4 fb2 = *(const float4*)(fp + 4);
    const float v[8] = {fa.x, fa.y, fa.z, fa.w, fb2.x, fb2.y, fb2.z, fb2.w};
    V16 pk;
    if (kk0 < 128) {
#pragma unroll
      for (int j = 0; j < 8; ++j) pk.us[j] = f2bf(-sA[kk0 + j] * v[j]);
    } else {
#pragma unroll
      for (int j = 0; j < 8; ++j) pk.us[j] = f2bf(gamma[kk0 + j] * v[j]);
    }
    *(uint4*)&As[i * 256 + (kk0 ^ ((i & 7) << 3))] = pk.v4;
  }
  __syncthreads();
  if (t < 128) {
    float kc = bvec[t];
#pragma unroll
    for (int g = 0; g < 8; ++g) kc += kcp[t][g];
    KcS[t] = kc;
  }
  __syncthreads();

  // ---- MFMA: 16 waves, one 16x16 output tile each, K=256 ----
  {
    const int w  = t >> 6;        // wave 0..15
    const int l  = t & 63;
    const int tn = w & 7;         // col tile 0..7
    const int tm = w >> 3;        // row tile 0..1
    const int l16 = l & 15;
    const int lg  = l >> 4;       // k-group 0..3

    const int ar = tm * 16 + l16;            // A row (local)
    const int bc = tn * 16 + l16;            // B col (= output col)
    const int abase = ar * 256;
    const int bbase = bc * 256;
    const int aswz = (ar & 7) << 3;
    const int bswz = (bc & 7) << 3;

    f32x4 acc = {0.f, 0.f, 0.f, 0.f};
#pragma unroll
    for (int kc = 0; kc < 8; ++kc) {
      const int kk = kc * 32 + lg * 8;
      const short8 av = *(const short8*)&As[abase + (kk ^ aswz)];
      const short8 bv = *(const short8*)&Wb[bbase + (kk ^ bswz)];
      acc = __builtin_amdgcn_mfma_f32_16x16x32_bf16(av, bv, acc, 0, 0, 0);
    }

    const float kc2 = KcS[bc];
    float* ob = out + (size_t)b * (L_ * C_);
#pragma unroll
    for (int r = 0; r < 4; ++r) {
      const int m = tm * 16 + lg * 4 + r;    // output row (local)
      ob[(size_t)(1 + r0 + m) * C_ + bc] = acc[r] + kc2;
    }
  }
}

extern "C" void kernel_launch(void* const* d_in, const int* in_sizes, int n_in,
                              void* d_out, int out_size, void* d_ws, size_t ws_size,
                              hipStream_t stream) {
  const float* x     = (const float*)d_in[0];
  const float* gamma = (const float*)d_in[1];
  const float* beta  = (const float*)d_in[2];
  const float* W     = (const float*)d_in[3];
  const float* bvec  = (const float*)d_in[4];
  float* out = (float*)d_out;

  lnp_mfma_kernel<<<B_ * RB_, NTHR_, 0, stream>>>(x, gamma, beta, W, bvec, out);
}

// Round 4
// 19.423 us; speedup vs baseline: 1.2961x; 1.2301x over previous
//
#include <hip/hip_runtime.h>
#include <hip/hip_bf16.h>
#include <math.h>

// Shapes fixed by reference: B=2, L=385, C=128, N=384, 2C=256
// Verified identity (rounds 0-3 all passed with it):
//   out[b,1+i,c] = Kc[b,c] + sum_{kk=0}^{255} A2[b,i,kk] * W[c,kk]
//     A2[i,kk]  = -s_kk * F[i,kk]          (kk < 128)
//     A2[i,kk]  =  gamma[kk] * F[i,kk-128] (kk >= 128)
//     s_k       = gamma[k] / sqrt(var_j F[:,k] + eps)
//     Kc[c]     = b[c] + sum_kk W[c,kk] * fac[kk]
//     fac[kk]   = (kk<128) ? s_kk*M_kk + beta[kk] : beta[kk]
//     M_k       = sum_j softmax_j(s_k F[j,k]) F[j,k]
// Softmax shift: s*mean (exactly shift-invariant; |s(F-mu)| <= |gamma|*sqrt(N)
// so exp never overflows for any input). exp via v_exp_f32 (exp2, log2e
// folded into the per-channel scale).

#define B_  2
#define L_  385
#define C_  128
#define N_  384
#define EPS_ 1e-5f
#define MROWS_ 32
#define RB_  (N_ / MROWS_)   // 12 row-tiles per batch
#define NTHR_ 1024
#define JPT_ 48              // rows per h-group in stats passes
#define LOG2E_ 1.44269504088896340736f

typedef short short8 __attribute__((ext_vector_type(8)));
typedef float f32x4 __attribute__((ext_vector_type(4)));

union V16 { ushort us[8]; uint4 v4; };

__device__ inline ushort f2bf(float f) {  // f32 -> bf16, round-nearest-even
  uint32_t u = __builtin_bit_cast(uint32_t, f);
  u += 0x7fffu + ((u >> 16) & 1u);
  return (ushort)(u >> 16);
}

__device__ inline float fast_exp2(float xv) {
#if __has_builtin(__builtin_amdgcn_exp2f)
  return __builtin_amdgcn_exp2f(xv);
#else
  float r;
  asm("v_exp_f32 %0, %1" : "=v"(r) : "v"(xv));
  return r;
#endif
}

__global__ __launch_bounds__(NTHR_, 1) void lnp_mfma_kernel(
    const float* __restrict__ x, const float* __restrict__ gamma,
    const float* __restrict__ beta, const float* __restrict__ W,
    const float* __restrict__ bvec, float* __restrict__ out) {
  __shared__ float p_s1[8][128], p_s2[8][128];
  __shared__ float sA[128], slA[128], shA[128];
  __shared__ float fac[256];
  __shared__ float KcS[128];
  __shared__ __align__(16) ushort Wb[128 * 256];    // [c][kk^((c&7)<<3)] bf16
  __shared__ __align__(16) ushort As[MROWS_ * 256]; // [i][kk^((i&7)<<3)] bf16

  const int blk = blockIdx.x;
  const int b   = blk / RB_;
  const int rt  = blk % RB_;
  const int r0  = rt * MROWS_;
  const int t   = threadIdx.x;
  const int c0  = t & 127;
  const int h   = t >> 7;

  const float* Fb = x + (size_t)b * (L_ * C_) + C_;  // F[j][c] = Fb[j*128+c]

  // cls-token passthrough
  if (rt == 0 && t < C_)
    out[(size_t)b * (L_ * C_) + t] = x[(size_t)b * (L_ * C_) + t];

  // ---- P1: per-channel sum / sumsq (coalesced rows) ----
  {
    const float* p = Fb + (size_t)h * JPT_ * C_ + c0;
    float s1 = 0.f, s2 = 0.f;
#pragma unroll 8
    for (int jj = 0; jj < JPT_; ++jj) {
      const float f = p[(size_t)jj * C_];
      s1 += f; s2 = fmaf(f, f, s2);
    }
    p_s1[h][c0] = s1; p_s2[h][c0] = s2;
  }
  __syncthreads();

  // ---- P2: finalize scale; shift = sl*mean ----
  if (t < 128) {
    float s1 = 0.f, s2 = 0.f;
#pragma unroll
    for (int g = 0; g < 8; ++g) { s1 += p_s1[g][t]; s2 += p_s2[g][t]; }
    const float mean = s1 * (1.0f / N_);
    const float var  = fmaxf(s2 * (1.0f / N_) - mean * mean, 0.0f);
    const float s    = gamma[t] * rsqrtf(var + EPS_);
    const float sl   = s * LOG2E_;
    sA[t] = s; slA[t] = sl; shA[t] = sl * mean;
    fac[128 + t] = beta[128 + t];   // stats-independent half of fac
  }
  __syncthreads();

  // ---- P3: softmax moments + As build + W->bf16 conversion ----
  {
    const float sl = slA[c0], sh = shA[c0];
    const float* p = Fb + (size_t)h * JPT_ * C_ + c0;
    float se = 0.f, sef = 0.f;
#pragma unroll 8
    for (int jj = 0; jj < JPT_; ++jj) {
      const float f = p[(size_t)jj * C_];
      const float e = fast_exp2(fmaf(sl, f, -sh));
      se += e; sef = fmaf(e, f, sef);
    }
    p_s1[h][c0] = se; p_s2[h][c0] = sef;
  }
  {
    // As: thread owns row i = t>>5, 8-kk chunk kk0 = (t&31)*8
    const int i   = t >> 5;
    const int kk0 = (t & 31) * 8;
    const int ks  = (kk0 < 128) ? kk0 : kk0 - 128;
    const float* fp = &Fb[(size_t)(r0 + i) * C_ + ks];
    const float4 fa = *(const float4*)fp;
    const float4 fb2 = *(const float4*)(fp + 4);
    const float v[8] = {fa.x, fa.y, fa.z, fa.w, fb2.x, fb2.y, fb2.z, fb2.w};
    V16 pk;
    if (kk0 < 128) {
#pragma unroll
      for (int j = 0; j < 8; ++j) pk.us[j] = f2bf(-sA[kk0 + j] * v[j]);
    } else {
#pragma unroll
      for (int j = 0; j < 8; ++j) pk.us[j] = f2bf(gamma[kk0 + j] * v[j]);
    }
    *(uint4*)&As[i * 256 + (kk0 ^ ((i & 7) << 3))] = pk.v4;
  }
  {
    // Wb: thread owns row c = t>>3, 32-kk segment kb = (t&7)*32
    const int c  = t >> 3;
    const int kb = (t & 7) * 32;
#pragma unroll
    for (int q = 0; q < 4; ++q) {
      const int kk = kb + q * 8;
      const float* wp = &W[c * 256 + kk];
      const float4 wa = *(const float4*)wp;
      const float4 wb2 = *(const float4*)(wp + 4);
      const float v[8] = {wa.x, wa.y, wa.z, wa.w, wb2.x, wb2.y, wb2.z, wb2.w};
      V16 pk;
#pragma unroll
      for (int j = 0; j < 8; ++j) pk.us[j] = f2bf(v[j]);
      *(uint4*)&Wb[c * 256 + (kk ^ ((c & 7) << 3))] = pk.v4;
    }
  }
  __syncthreads();

  // ---- P4: finalize fac (needs softmax moments) ----
  if (t < 128) {
    float se = 0.f, sef = 0.f;
#pragma unroll
    for (int g = 0; g < 8; ++g) { se += p_s1[g][t]; sef += p_s2[g][t]; }
    fac[t] = fmaf(sA[t], sef / se, beta[t]);
  }
  __syncthreads();

  // ---- P5: Kc = b + W.fac via L2-warm W re-read + shfl segment reduce ----
  {
    const int c  = t >> 3;
    const int kb = (t & 7) * 32;
    const float* wp = &W[c * 256 + kb];
    float kc = 0.f;
#pragma unroll
    for (int q = 0; q < 8; ++q) {
      const float4 w4 = *(const float4*)(wp + q * 4);
      kc = fmaf(w4.x, fac[kb + q * 4 + 0], kc);
      kc = fmaf(w4.y, fac[kb + q * 4 + 1], kc);
      kc = fmaf(w4.z, fac[kb + q * 4 + 2], kc);
      kc = fmaf(w4.w, fac[kb + q * 4 + 3], kc);
    }
    kc += __shfl_xor(kc, 1);
    kc += __shfl_xor(kc, 2);
    kc += __shfl_xor(kc, 4);
    if ((t & 7) == 0) KcS[c] = kc + bvec[c];
  }
  __syncthreads();

  // ---- P6: MFMA, 16 waves x one 16x16 tile, K=256 (verified layout) ----
  {
    const int w   = t >> 6;
    const int l   = t & 63;
    const int tn  = w & 7;
    const int tm  = w >> 3;
    const int l16 = l & 15;
    const int lg  = l >> 4;

    const int ar = tm * 16 + l16;
    const int bc = tn * 16 + l16;
    const int abase = ar * 256;
    const int bbase = bc * 256;
    const int aswz = (ar & 7) << 3;
    const int bswz = (bc & 7) << 3;

    f32x4 acc = {0.f, 0.f, 0.f, 0.f};
#pragma unroll
    for (int kt = 0; kt < 8; ++kt) {
      const int kk = kt * 32 + lg * 8;
      const short8 av = *(const short8*)&As[abase + (kk ^ aswz)];
      const short8 bv = *(const short8*)&Wb[bbase + (kk ^ bswz)];
      acc = __builtin_amdgcn_mfma_f32_16x16x32_bf16(av, bv, acc, 0, 0, 0);
    }

    const float kcv = KcS[bc];
    float* ob = out + (size_t)b * (L_ * C_);
#pragma unroll
    for (int r = 0; r < 4; ++r) {
      const int m = tm * 16 + lg * 4 + r;
      ob[(size_t)(1 + r0 + m) * C_ + bc] = acc[r] + kcv;
    }
  }
}

extern "C" void kernel_launch(void* const* d_in, const int* in_sizes, int n_in,
                              void* d_out, int out_size, void* d_ws, size_t ws_size,
                              hipStream_t stream) {
  const float* x     = (const float*)d_in[0];
  const float* gamma = (const float*)d_in[1];
  const float* beta  = (const float*)d_in[2];
  const float* W     = (const float*)d_in[3];
  const float* bvec  = (const float*)d_in[4];
  float* out = (float*)d_out;

  lnp_mfma_kernel<<<B_ * RB_, NTHR_, 0, stream>>>(x, gamma, beta, W, bvec, out);
}

// Round 5
// 15.021 us; speedup vs baseline: 1.6759x; 1.2931x over previous
//
#include <hip/hip_runtime.h>
#include <hip/hip_bf16.h>
#include <math.h>

// Shapes fixed by reference: B=2, L=385, C=128, N=384, 2C=256
// Verified identity (rounds 0-4 all passed with it):
//   out[b,1+i,c] = b[c] + sum_{kk=0}^{255} (A2[b,i,kk] + fac[b,kk]) * W[c,kk]
//     A2[i,kk]  = -s_kk * F[i,kk]          (kk < 128)
//     A2[i,kk]  =  gamma[kk] * F[i,kk-128] (kk >= 128)
//     fac[kk]   = (kk<128) ? s_kk*M_kk + beta[kk] : beta[kk]
//     s_k       = gamma[k] / sqrt(var_j F[:,k] + eps)
//     M_k       = sum_j softmax_j(s_k F[j,k]) F[j,k]
// (Kc of earlier rounds folded into the A operand: adding fac to every A row
//  makes the GEMM emit Kc-b[c] automatically.)
// Softmax shift: s*mean (exact shift-invariance; |s*(F-mu)| <= |gamma|*sqrt(N)
// so exp2 never overflows). exp via v_exp_f32 with log2e folded into scale.
// F cached in registers between the two statistics passes.

#define B_  2
#define L_  385
#define C_  128
#define N_  384
#define EPS_ 1e-5f
#define MROWS_ 32
#define RB_  (N_ / MROWS_)   // 12 row-tiles per batch
#define NTHR_ 1024
#define LOG2E_ 1.44269504088896340736f

typedef short short8 __attribute__((ext_vector_type(8)));
typedef float f32x4 __attribute__((ext_vector_type(4)));

union V16 { ushort us[8]; uint4 v4; };

__device__ inline ushort f2bf(float f) {
  __hip_bfloat16 hb = __float2bfloat16(f);   // hw RNE (v_cvt_pk_bf16_f32)
  return __builtin_bit_cast(ushort, hb);
}

__device__ inline float fast_exp2(float xv) {
#if __has_builtin(__builtin_amdgcn_exp2f)
  return __builtin_amdgcn_exp2f(xv);
#else
  float r;
  asm("v_exp_f32 %0, %1" : "=v"(r) : "v"(xv));
  return r;
#endif
}

__global__ __launch_bounds__(NTHR_, 1) void lnp_kernel(
    const float* __restrict__ x, const float* __restrict__ gamma,
    const float* __restrict__ beta, const float* __restrict__ W,
    const float* __restrict__ bvec, float* __restrict__ out) {
  __shared__ __align__(16) float p1[32][128];
  __shared__ __align__(16) float p2[32][128];
  __shared__ __align__(16) float sA[128], slA[128], shA[128];
  __shared__ __align__(16) float facL[256];
  __shared__ __align__(16) ushort Wb[128 * 256];    // [c][kk^((c&7)<<3)] bf16
  __shared__ __align__(16) ushort As[MROWS_ * 256]; // [i][kk^((i&7)<<3)] bf16

  const int blk = blockIdx.x;
  const int b   = blk / RB_;
  const int rt  = blk % RB_;
  const int r0  = rt * MROWS_;
  const int t   = threadIdx.x;

  const float* Fb = x + (size_t)b * (L_ * C_) + C_;  // F[j][c] = Fb[j*128+c]

  // cls-token passthrough
  if (rt == 0 && t < C_)
    out[(size_t)b * (L_ * C_) + t] = x[(size_t)b * (L_ * C_) + t];

  // ---- P1: vectorized F load (cached in regs) + sum/sumsq partials;
  //      Wb bf16 conversion overlapped with the load latency ----
  const int tc = t & 31;        // channel quad index
  const int c4 = tc * 4;        // first of 4 owned channels
  const int h  = t >> 5;        // row group 0..31 (rows h*12 .. h*12+11)
  float4 v[12];
  {
    const float* p = Fb + (size_t)(h * 12) * C_ + c4;
#pragma unroll
    for (int r = 0; r < 12; ++r)
      v[r] = *(const float4*)(p + (size_t)r * C_);

    float ax = 0.f, ay = 0.f, az = 0.f, aw = 0.f;
    float qx = 0.f, qy = 0.f, qz = 0.f, qw = 0.f;
#pragma unroll
    for (int r = 0; r < 12; ++r) {
      ax += v[r].x; qx = fmaf(v[r].x, v[r].x, qx);
      ay += v[r].y; qy = fmaf(v[r].y, v[r].y, qy);
      az += v[r].z; qz = fmaf(v[r].z, v[r].z, qz);
      aw += v[r].w; qw = fmaf(v[r].w, v[r].w, qw);
    }
    float4 s1 = {ax, ay, az, aw};
    float4 s2 = {qx, qy, qz, qw};
    *(float4*)&p1[h][c4] = s1;
    *(float4*)&p2[h][c4] = s2;
  }
  {
    // Wb: thread owns row c = t>>3, 32-kk segment kb = (t&7)*32
    const int c  = t >> 3;
    const int kb = (t & 7) * 32;
    const int swz = (c & 7) << 3;
#pragma unroll
    for (int q = 0; q < 4; ++q) {
      const int kk = kb + q * 8;
      const float* wp = &W[c * 256 + kk];
      const float4 wa  = *(const float4*)wp;
      const float4 wb2 = *(const float4*)(wp + 4);
      V16 pk;
      pk.us[0] = f2bf(wa.x);  pk.us[1] = f2bf(wa.y);
      pk.us[2] = f2bf(wa.z);  pk.us[3] = f2bf(wa.w);
      pk.us[4] = f2bf(wb2.x); pk.us[5] = f2bf(wb2.y);
      pk.us[6] = f2bf(wb2.z); pk.us[7] = f2bf(wb2.w);
      *(uint4*)&Wb[c * 256 + (kk ^ swz)] = pk.v4;
    }
  }
  __syncthreads();  // B1

  // ---- stats finalize (t<128): s, log2-scale, shift ----
  if (t < 128) {
    float s1 = 0.f, s2 = 0.f;
#pragma unroll
    for (int g = 0; g < 32; ++g) { s1 += p1[g][t]; s2 += p2[g][t]; }
    const float mean = s1 * (1.0f / N_);
    const float var  = fmaxf(s2 * (1.0f / N_) - mean * mean, 0.0f);
    const float s    = gamma[t] * rsqrtf(var + EPS_);
    const float sl   = s * LOG2E_;
    sA[t] = s; slA[t] = sl; shA[t] = sl * mean;
    facL[128 + t] = beta[128 + t];     // stats-independent half of fac
  }
  __syncthreads();  // B2

  // ---- P3: softmax moments from cached regs (pure VALU) ----
  {
    const float4 sl4 = *(const float4*)&slA[c4];
    const float4 sh4 = *(const float4*)&shA[c4];
    float ex = 0.f, ey = 0.f, ez = 0.f, ew = 0.f;
    float fx = 0.f, fy = 0.f, fz = 0.f, fw = 0.f;
#pragma unroll
    for (int r = 0; r < 12; ++r) {
      const float e0 = fast_exp2(fmaf(sl4.x, v[r].x, -sh4.x));
      const float e1 = fast_exp2(fmaf(sl4.y, v[r].y, -sh4.y));
      const float e2 = fast_exp2(fmaf(sl4.z, v[r].z, -sh4.z));
      const float e3 = fast_exp2(fmaf(sl4.w, v[r].w, -sh4.w));
      ex += e0; fx = fmaf(e0, v[r].x, fx);
      ey += e1; fy = fmaf(e1, v[r].y, fy);
      ez += e2; fz = fmaf(e2, v[r].z, fz);
      ew += e3; fw = fmaf(e3, v[r].w, fw);
    }
    float4 se = {ex, ey, ez, ew};
    float4 sf = {fx, fy, fz, fw};
    *(float4*)&p1[h][c4] = se;
    *(float4*)&p2[h][c4] = sf;
  }

  // ---- issue As row loads early (independent of fac) ----
  const int ai  = t >> 5;            // local row 0..31
  const int kk0 = (t & 31) * 8;      // kk chunk start
  const int ks  = kk0 & 127;         // source channel
  float4 af0, af1, g40 = {0,0,0,0}, g41 = {0,0,0,0};
  {
    const float* fp = &Fb[(size_t)(r0 + ai) * C_ + ks];
    af0 = *(const float4*)fp;
    af1 = *(const float4*)(fp + 4);
    if (kk0 >= 128) {
      g40 = *(const float4*)&gamma[kk0];
      g41 = *(const float4*)&gamma[kk0 + 4];
    }
  }
  __syncthreads();  // B3

  // ---- upper-half As (beta branch, fac already known) ||
  //      fac finalize (t<128) ----
  const int aswz_w = (ai & 7) << 3;
  if (kk0 >= 128) {
    const float4 fc0 = *(const float4*)&facL[kk0];
    const float4 fc1 = *(const float4*)&facL[kk0 + 4];
    V16 pk;
    pk.us[0] = f2bf(fmaf(g40.x, af0.x, fc0.x));
    pk.us[1] = f2bf(fmaf(g40.y, af0.y, fc0.y));
    pk.us[2] = f2bf(fmaf(g40.z, af0.z, fc0.z));
    pk.us[3] = f2bf(fmaf(g40.w, af0.w, fc0.w));
    pk.us[4] = f2bf(fmaf(g41.x, af1.x, fc1.x));
    pk.us[5] = f2bf(fmaf(g41.y, af1.y, fc1.y));
    pk.us[6] = f2bf(fmaf(g41.z, af1.z, fc1.z));
    pk.us[7] = f2bf(fmaf(g41.w, af1.w, fc1.w));
    *(uint4*)&As[ai * 256 + (kk0 ^ aswz_w)] = pk.v4;
  }
  if (t < 128) {
    float se = 0.f, sf = 0.f;
#pragma unroll
    for (int g = 0; g < 32; ++g) { se += p1[g][t]; sf += p2[g][t]; }
    facL[t] = fmaf(sA[t], sf / se, beta[t]);
  }
  __syncthreads();  // B4

  // ---- lower-half As (needs fac) ----
  if (kk0 < 128) {
    const float4 sa0 = *(const float4*)&sA[kk0];
    const float4 sa1 = *(const float4*)&sA[kk0 + 4];
    const float4 fc0 = *(const float4*)&facL[kk0];
    const float4 fc1 = *(const float4*)&facL[kk0 + 4];
    V16 pk;
    pk.us[0] = f2bf(fmaf(-sa0.x, af0.x, fc0.x));
    pk.us[1] = f2bf(fmaf(-sa0.y, af0.y, fc0.y));
    pk.us[2] = f2bf(fmaf(-sa0.z, af0.z, fc0.z));
    pk.us[3] = f2bf(fmaf(-sa0.w, af0.w, fc0.w));
    pk.us[4] = f2bf(fmaf(-sa1.x, af1.x, fc1.x));
    pk.us[5] = f2bf(fmaf(-sa1.y, af1.y, fc1.y));
    pk.us[6] = f2bf(fmaf(-sa1.z, af1.z, fc1.z));
    pk.us[7] = f2bf(fmaf(-sa1.w, af1.w, fc1.w));
    *(uint4*)&As[ai * 256 + (kk0 ^ aswz_w)] = pk.v4;
  }
  __syncthreads();  // B5

  // ---- MFMA: 16 waves x one 16x16 tile, K=256 (verified layout) ----
  {
    const int w   = t >> 6;
    const int l   = t & 63;
    const int tn  = w & 7;
    const int tm  = w >> 3;
    const int l16 = l & 15;
    const int lg  = l >> 4;

    const int ar = tm * 16 + l16;
    const int bc = tn * 16 + l16;
    const int abase = ar * 256;
    const int bbase = bc * 256;
    const int aswz = (ar & 7) << 3;
    const int bswz = (bc & 7) << 3;

    f32x4 acc = {0.f, 0.f, 0.f, 0.f};
#pragma unroll
    for (int kt = 0; kt < 8; ++kt) {
      const int kk = kt * 32 + lg * 8;
      const short8 av = *(const short8*)&As[abase + (kk ^ aswz)];
      const short8 bv = *(const short8*)&Wb[bbase + (kk ^ bswz)];
      acc = __builtin_amdgcn_mfma_f32_16x16x32_bf16(av, bv, acc, 0, 0, 0);
    }

    const float bb = bvec[bc];
    float* ob = out + (size_t)b * (L_ * C_);
#pragma unroll
    for (int r = 0; r < 4; ++r) {
      const int m = tm * 16 + lg * 4 + r;
      ob[(size_t)(1 + r0 + m) * C_ + bc] = acc[r] + bb;
    }
  }
}

extern "C" void kernel_launch(void* const* d_in, const int* in_sizes, int n_in,
                              void* d_out, int out_size, void* d_ws, size_t ws_size,
                              hipStream_t stream) {
  const float* x     = (const float*)d_in[0];
  const float* gamma = (const float*)d_in[1];
  const float* beta  = (const float*)d_in[2];
  const float* W     = (const float*)d_in[3];
  const float* bvec  = (const float*)d_in[4];
  float* out = (float*)d_out;

  lnp_kernel<<<B_ * RB_, NTHR_, 0, stream>>>(x, gamma, beta, W, bvec, out);
}